// Round 4
// baseline (430.302 us; speedup 1.0000x reference)
//
#include <hip/hip_runtime.h>
#include <hip/hip_bf16.h>
#include <stdint.h>

#define L_ 4
#define B_ 128
#define H_ 4096
#define BK 128
#define BN 32
#define KIT 128               // L_*H_/BK iterations
#define NTHR 256
#define WBYTES (BN*BK*2)      // 8192 B : W tile 32 x 128 fp16 (256 B rows)

typedef _Float16 f16x8 __attribute__((ext_vector_type(8)));
typedef float    f32x4 __attribute__((ext_vector_type(4)));
typedef float    f4    __attribute__((ext_vector_type(4)));
typedef uint32_t u32x4 __attribute__((ext_vector_type(4)));
typedef uint32_t u32x2 __attribute__((ext_vector_type(2)));

// RNE f32 -> fp16 pair packed into u32 (v_cvt_f16_f32 is round-nearest-even)
__device__ __forceinline__ uint32_t pack2(float a, float b) {
  const _Float16 ha = (_Float16)a;
  const _Float16 hb = (_Float16)b;
  const uint32_t ua = (uint32_t)__builtin_bit_cast(uint16_t, ha);
  const uint32_t ub = (uint32_t)__builtin_bit_cast(uint16_t, hb);
  return ua | (ub << 16);
}

__global__ void cvt_states_kernel(const float* __restrict__ x,
                                  uint32_t* __restrict__ y, int n4) {
  const int i = blockIdx.x * blockDim.x + threadIdx.x;
  if (i < n4) {
    f4 v = reinterpret_cast<const f4*>(x)[i];
    u32x2 o;
    o.x = pack2(v.x, v.y);
    o.y = pack2(v.z, v.w);
    reinterpret_cast<u32x2*>(y)[i] = o;
  }
}

// counted-wait barrier: own ds ops complete, global loads stay in flight.
__device__ __forceinline__ void bar_lgkm0() {
  __builtin_amdgcn_sched_barrier(0);
  asm volatile("s_waitcnt lgkmcnt(0)");
  __builtin_amdgcn_sched_barrier(0);
  __builtin_amdgcn_s_barrier();
  __builtin_amdgcn_sched_barrier(0);
}

template<bool USE_WS>
__global__ __launch_bounds__(NTHR, 2)
void net_gemm_kernel(const float* __restrict__ statesf,
                     const uint16_t* __restrict__ statesh,
                     const float* __restrict__ Wm,
                     const float* __restrict__ ext,
                     float* __restrict__ out)
{
  __shared__ uint8_t lds[2 * WBYTES];     // 16 KB: W only, double-buffered

  const int tid  = threadIdx.x;
  const int bid  = blockIdx.x;
  const int t    = bid >> 7;              // 0..3
  const int n0   = (bid & 127) * BN;      // output-col tile

  const int wv   = tid >> 6;              // wave 0..3
  const int lane = tid & 63;
  const int lid  = lane & 15;
  const int lh   = lane >> 4;

  // ---- A direct-load base: lane (lid,lh) of wave wv reads rows wv*32+mf*16+lid,
  //      16 B at k-offset kk*32 + lh*8 (fp16 units) ----
  const uint16_t* ah_base = USE_WS ? (statesh + (size_t)(wv * 32 + lid) * H_ + lh * 8) : nullptr;
  const float*    af_base = statesf + (size_t)(wv * 32 + lid) * H_ + lh * 8;

  // ---- W staging map: thread -> row wrow (0..31), 16 f32 at col (tid&7)*16 ----
  const int wrow = tid >> 3;              // 0..31
  const int wc16 = (tid & 7) * 16;        // f32 col
  const float* w_base = Wm + ((size_t)(t * L_) * H_ + (size_t)(n0 + wrow)) * H_ + wc16;
  const uint32_t cb = (uint32_t)(tid & 7) * 32;  // byte col in 256B LDS row
  const uint32_t w_st0 = (uint32_t)wrow * 256 + (cb ^ (((uint32_t)wrow & 7) << 4));
  const uint32_t w_st1 = (uint32_t)wrow * 256 + ((cb + 16) ^ (((uint32_t)wrow & 7) << 4));

  // ---- LDS read offsets for W (B-operand) fragments ----
  uint32_t b_rd[2][4];
  #pragma unroll
  for (int nf = 0; nf < 2; ++nf)
    #pragma unroll
    for (int kk = 0; kk < 4; ++kk) {
      const uint32_t row = (uint32_t)(nf * 16 + lid);
      b_rd[nf][kk] = row * 256 +
                     (((uint32_t)(kk * 64 + lh * 16)) ^ (((uint32_t)lid & 7) << 4));
    }

  f32x4 acc[2][2] = {};

  // register double buffers (static indexing only)
  f16x8 aA[2][4], aB[2][4];               // A fragments [mf][kk]
  f4    wfA[4], wfB[4];                   // W staging, 16 f32

  auto LOADA = [&](int kidx, f16x8 (&ar)[2][4]) {
    const int s  = kidx >> 5;
    const int h0 = (kidx & 31) << 7;
    if constexpr (USE_WS) {
      const uint16_t* p = ah_base + (size_t)s * (B_ * H_) + h0;
      #pragma unroll
      for (int mf = 0; mf < 2; ++mf)
        #pragma unroll
        for (int kk = 0; kk < 4; ++kk)
          ar[mf][kk] = *reinterpret_cast<const f16x8*>(p + mf * (16 * H_) + kk * 32);
    } else {
      const float* p = af_base + (size_t)s * (B_ * H_) + h0;
      #pragma unroll
      for (int mf = 0; mf < 2; ++mf)
        #pragma unroll
        for (int kk = 0; kk < 4; ++kk) {
          f4 lo = *reinterpret_cast<const f4*>(p + mf * (16 * H_) + kk * 32);
          f4 hi = *reinterpret_cast<const f4*>(p + mf * (16 * H_) + kk * 32 + 4);
          u32x4 v;
          v.x = pack2(lo.x, lo.y); v.y = pack2(lo.z, lo.w);
          v.z = pack2(hi.x, hi.y); v.w = pack2(hi.z, hi.w);
          ar[mf][kk] = __builtin_bit_cast(f16x8, v);
        }
    }
  };

  auto LOADW = [&](int kidx, f4 (&wf)[4]) {
    const int s  = kidx >> 5;
    const int h0 = (kidx & 31) << 7;
    const float* wp = w_base + (size_t)s * ((size_t)H_ * H_) + h0;
    #pragma unroll
    for (int j = 0; j < 4; ++j)
      wf[j] = __builtin_nontemporal_load(reinterpret_cast<const f4*>(wp + j * 4));
  };

  auto WRITEW = [&](uint8_t* base, f4 (&wf)[4]) {
    u32x4 v0, v1;
    v0.x = pack2(wf[0].x, wf[0].y); v0.y = pack2(wf[0].z, wf[0].w);
    v0.z = pack2(wf[1].x, wf[1].y); v0.w = pack2(wf[1].z, wf[1].w);
    v1.x = pack2(wf[2].x, wf[2].y); v1.y = pack2(wf[2].z, wf[2].w);
    v1.z = pack2(wf[3].x, wf[3].y); v1.w = pack2(wf[3].z, wf[3].w);
    *reinterpret_cast<u32x4*>(base + w_st0) = v0;
    *reinterpret_cast<u32x4*>(base + w_st1) = v1;
  };

  auto COMPUTE = [&](const uint8_t* base, f16x8 (&ar)[2][4]) {
    f16x8 bv[2][4];
    #pragma unroll
    for (int nf = 0; nf < 2; ++nf)
      #pragma unroll
      for (int kk = 0; kk < 4; ++kk)
        bv[nf][kk] = *reinterpret_cast<const f16x8*>(base + b_rd[nf][kk]);
    #pragma unroll
    for (int kk = 0; kk < 4; ++kk)
      #pragma unroll
      for (int mf = 0; mf < 2; ++mf)
        #pragma unroll
        for (int nf = 0; nf < 2; ++nf)
          acc[mf][nf] = __builtin_amdgcn_mfma_f32_16x16x32_f16(
              ar[mf][kk], bv[nf][kk], acc[mf][nf], 0, 0, 0);
  };

  uint8_t* buf0 = lds;
  uint8_t* buf1 = lds + WBYTES;

  // prologue: W tiles 0,1 and A tile 0 in flight; stage W0 into LDS
  LOADW(0, wfA);
  LOADW(1, wfB);
  LOADA(0, aA);
  WRITEW(buf0, wfA);     // counted vmcnt: W1 + A0 loads stay in flight
  bar_lgkm0();

  #pragma unroll 1
  for (int k = 0; k < KIT; k += 2) {
    // even: compute tile k (buf0, aA); stage W(k+1); prefetch W(k+2), A(k+1)
    if (k + 2 < KIT) LOADW(k + 2, wfA);
    LOADA(k + 1, aB);
    COMPUTE(buf0, aA);
    WRITEW(buf1, wfB);
    bar_lgkm0();

    // odd: compute tile k+1 (buf1, aB); stage W(k+2); prefetch W(k+3), A(k+2)
    if (k + 3 < KIT) LOADW(k + 3, wfB);
    if (k + 2 < KIT) LOADA(k + 2, aA);
    COMPUTE(buf1, aB);
    if (k + 2 < KIT) {
      WRITEW(buf0, wfA);
      bar_lgkm0();
    }
  }

  // ---- epilogue: out = tanh(acc + ext), C/D layout col=lane&15, row=lh*4+j ----
  #pragma unroll
  for (int mf = 0; mf < 2; ++mf)
    #pragma unroll
    for (int nf = 0; nf < 2; ++nf)
      #pragma unroll
      for (int j = 0; j < 4; ++j) {
        const int brow = wv * 32 + mf * 16 + lh * 4 + j;
        const int ocol = n0 + nf * 16 + lid;
        const size_t idx = ((size_t)(t * B_ + brow)) * H_ + ocol;
        out[idx] = tanhf(acc[mf][nf][j] + ext[idx]);
      }
}

extern "C" void kernel_launch(void* const* d_in, const int* in_sizes, int n_in,
                              void* d_out, int out_size, void* d_ws, size_t ws_size,
                              hipStream_t stream) {
  const float* states = (const float*)d_in[0];
  const float* W      = (const float*)d_in[1];
  const float* ext    = (const float*)d_in[2];
  float* out          = (float*)d_out;

  const size_t nstates = (size_t)L_ * B_ * H_;       // 2,097,152 elements
  if (ws_size >= nstates * sizeof(uint16_t)) {
    const int n4 = (int)(nstates / 4);
    cvt_states_kernel<<<(n4 + 255) / 256, 256, 0, stream>>>(states, (uint32_t*)d_ws, n4);
    net_gemm_kernel<true><<<512, NTHR, 0, stream>>>(
        states, (const uint16_t*)d_ws, W, ext, out);
  } else {
    net_gemm_kernel<false><<<512, NTHR, 0, stream>>>(
        states, nullptr, W, ext, out);
  }
}

// Round 5
// 265.219 us; speedup vs baseline: 1.6224x; 1.6224x over previous
//
#include <hip/hip_runtime.h>
#include <hip/hip_bf16.h>
#include <stdint.h>

#define L_ 4
#define B_ 128
#define H_ 4096
#define BK 64
#define BN 32
#define KIT 256               // L_*H_/BK
#define NTHR 256
#define ABYTES (128*BK*2)     // 16384 B : A tile 128 x 64 fp16 (128 B rows)
#define WBYTES (BN*BK*2)      // 4096 B  : W tile 32 x 64 fp16 (128 B rows)
#define BUFB   (ABYTES+WBYTES)// 20480 B per buffer, 3 buffers = 60 KB

typedef _Float16 f16x8 __attribute__((ext_vector_type(8)));
typedef float    f32x4 __attribute__((ext_vector_type(4)));
typedef float    f4    __attribute__((ext_vector_type(4)));
typedef uint32_t u32x4 __attribute__((ext_vector_type(4)));
typedef uint32_t u32x2 __attribute__((ext_vector_type(2)));

// RNE f32 -> fp16 pair packed into u32 (v_cvt_f16_f32 is round-nearest-even)
__device__ __forceinline__ uint32_t pack2(float a, float b) {
  const _Float16 ha = (_Float16)a;
  const _Float16 hb = (_Float16)b;
  const uint32_t ua = (uint32_t)__builtin_bit_cast(uint16_t, ha);
  const uint32_t ub = (uint32_t)__builtin_bit_cast(uint16_t, hb);
  return ua | (ub << 16);
}

__global__ void cvt_states_kernel(const float* __restrict__ x,
                                  uint32_t* __restrict__ y, int n4) {
  const int i = blockIdx.x * blockDim.x + threadIdx.x;
  if (i < n4) {
    f4 v = reinterpret_cast<const f4*>(x)[i];
    u32x2 o;
    o.x = pack2(v.x, v.y);
    o.y = pack2(v.z, v.w);
    reinterpret_cast<u32x2*>(y)[i] = o;
  }
}

// async global->LDS, 16 B per lane; LDS dest is wave-uniform base + lane*16
__device__ __forceinline__ void gld_lds16(const void* g, void* l) {
  __builtin_amdgcn_global_load_lds(
      (const __attribute__((address_space(1))) void*)g,
      (__attribute__((address_space(3))) void*)l, 16, 0, 0);
}

// counted-wait barrier: own ds ops done, N newest global loads may stay in flight
#define BAR_VM(N_) do {                                          \
    __builtin_amdgcn_sched_barrier(0);                           \
    asm volatile("s_waitcnt vmcnt(" #N_ ") lgkmcnt(0)" ::: "memory"); \
    __builtin_amdgcn_sched_barrier(0);                           \
    __builtin_amdgcn_s_barrier();                                \
    __builtin_amdgcn_sched_barrier(0);                           \
  } while (0)

// ============================ main kernel (ws fp16 A) ============================
__global__ __launch_bounds__(NTHR, 2)
void net_gemm_kernel(const uint16_t* __restrict__ statesh,
                     const float* __restrict__ Wm,
                     const float* __restrict__ ext,
                     float* __restrict__ out)
{
  __shared__ __align__(16) uint8_t lds[3 * BUFB];   // 60 KB, triple-buffered

  const int tid  = threadIdx.x;
  const int bid  = blockIdx.x;
  const int t    = bid >> 7;              // 0..3
  const int n0   = (bid & 127) * BN;      // output-col tile

  const int wv   = tid >> 6;              // wave 0..3
  const int lane = tid & 63;
  const int lid  = lane & 15;
  const int lh   = lane >> 4;

  // ---- A DMA source offsets: LDS linear slot o holds element (row, cb^((row&7)<<4))
  //      o = j*4096 + wv*1024 + lane*16 ; row=o>>7, cb=o&127 ----
  uint32_t a_src[4];
  #pragma unroll
  for (int j = 0; j < 4; ++j) {
    const uint32_t row = (uint32_t)(j * 32 + wv * 8 + (lane >> 3));
    const uint32_t cb  = (uint32_t)(lane & 7) * 16;
    a_src[j] = row * (H_ * 2) + (cb ^ ((row & 7) << 4));
  }

  // ---- W staging map: thread -> rows (tid>>4) and +16, 4 f32 at col (tid&15)*4 ----
  const int wrow = tid >> 4;              // 0..15
  const int wcol = (tid & 15) * 4;
  const float* w_base = Wm + ((size_t)t * L_ * H_ + (size_t)(n0 + wrow)) * H_ + wcol;
  const uint32_t w_st0 =
      (uint32_t)ABYTES + (uint32_t)wrow * 128 + (((uint32_t)(tid & 15) * 8) ^ ((uint32_t)(wrow & 7) << 4));
  const uint32_t w_st1 = w_st0 + 16 * 128;

  // ---- LDS read offsets for MFMA fragments ----
  uint32_t a_rd[2][2], b_rd[2][2];
  #pragma unroll
  for (int mf = 0; mf < 2; ++mf)
    #pragma unroll
    for (int kk = 0; kk < 2; ++kk) {
      const int row = wv * 32 + mf * 16 + lid;
      a_rd[mf][kk] = (uint32_t)row * 128 +
                     (((uint32_t)(kk * 64 + lh * 16)) ^ ((uint32_t)(lid & 7) << 4));
    }
  #pragma unroll
  for (int nf = 0; nf < 2; ++nf)
    #pragma unroll
    for (int kk = 0; kk < 2; ++kk) {
      const int row = nf * 16 + lid;
      b_rd[nf][kk] = (uint32_t)ABYTES + (uint32_t)row * 128 +
                     (((uint32_t)(kk * 64 + lh * 16)) ^ ((uint32_t)(lid & 7) << 4));
    }

  f32x4 acc[2][2] = {};
  f4 wf[2][4];                            // W reg staging, 2 sets (static indices only)

  auto LOADW = [&](int kidx, f4 (&w)[4]) {
    const int s  = kidx >> 6;
    const int h0 = (kidx & 63) << 6;
    const float* wp = w_base + (size_t)s * ((size_t)H_ * H_) + h0;
    w[0] = __builtin_nontemporal_load(reinterpret_cast<const f4*>(wp));
    w[1] = __builtin_nontemporal_load(reinterpret_cast<const f4*>(wp + 16 * (size_t)H_));
    w[2] = w[0];  // keep array shape; unused slots optimized away
    w[3] = w[1];
  };

  auto ALDS = [&](int kidx, int bufi) {
    const uint8_t* g = (const uint8_t*)statesh +
                       (size_t)(kidx >> 6) * (B_ * H_ * 2) + (size_t)(kidx & 63) * 128;
    uint8_t* l = lds + bufi * BUFB + wv * 1024;
    #pragma unroll
    for (int j = 0; j < 4; ++j)
      gld_lds16(g + a_src[j], l + j * 4096);
  };

  auto WRITEW = [&](int bufi, f4 (&w)[4]) {
    uint8_t* base = lds + bufi * BUFB;
    u32x2 w0, w1;
    w0.x = pack2(w[0].x, w[0].y); w0.y = pack2(w[0].z, w[0].w);
    w1.x = pack2(w[1].x, w[1].y); w1.y = pack2(w[1].z, w[1].w);
    *reinterpret_cast<u32x2*>(base + w_st0) = w0;
    *reinterpret_cast<u32x2*>(base + w_st1) = w1;
  };

  auto COMPUTE = [&](int bufi) {
    const uint8_t* base = lds + bufi * BUFB;
    f16x8 av[2][2], bv[2][2];
    #pragma unroll
    for (int mf = 0; mf < 2; ++mf)
      #pragma unroll
      for (int kk = 0; kk < 2; ++kk)
        av[mf][kk] = *reinterpret_cast<const f16x8*>(base + a_rd[mf][kk]);
    #pragma unroll
    for (int nf = 0; nf < 2; ++nf)
      #pragma unroll
      for (int kk = 0; kk < 2; ++kk)
        bv[nf][kk] = *reinterpret_cast<const f16x8*>(base + b_rd[nf][kk]);
    #pragma unroll
    for (int kk = 0; kk < 2; ++kk)
      #pragma unroll
      for (int mf = 0; mf < 2; ++mf)
        #pragma unroll
        for (int nf = 0; nf < 2; ++nf)
          acc[mf][nf] = __builtin_amdgcn_mfma_f32_16x16x32_f16(
              av[mf][kk], bv[nf][kk], acc[mf][nf], 0, 0, 0);
  };

  // prologue: W0,W1 regs + A0,A1 DMA in flight; stage W0; A0 must land (vmcnt(4))
  LOADW(0, wf[0]);
  LOADW(1, wf[1]);
  ALDS(0, 0);
  ALDS(1, 1);
  WRITEW(0, wf[0]);
  BAR_VM(4);

  // body j: load W(j+2)->wf[j&1], A-DMA(j+2)->buf[(j+2)%3]; compute buf[j%3];
  //         write W(j+1) from wf[(j+1)&1] -> buf[(j+1)%3]; barrier vmcnt(6)
  #define BODY(kk_, C_, N_, WT_, LE_) do {      \
      LOADW((kk_) + 2, wf[LE_]);                \
      ALDS((kk_) + 2, (N_));                    \
      COMPUTE((C_));                            \
      WRITEW((WT_), wf[1 - (LE_)]);             \
      BAR_VM(6);                                \
    } while (0)

  #pragma unroll 1
  for (int k = 0; k < 252; k += 6) {
    BODY(k + 0, 0, 2, 1, 0);
    BODY(k + 1, 1, 0, 2, 1);
    BODY(k + 2, 2, 1, 0, 0);
    BODY(k + 3, 0, 2, 1, 1);
    BODY(k + 4, 1, 0, 2, 0);
    BODY(k + 5, 2, 1, 0, 1);
  }
  // tail j = 252..255
  BODY(252, 0, 2, 1, 0);
  BODY(253, 1, 0, 2, 1);
  COMPUTE(2);                 // j=254: no more loads
  WRITEW(0, wf[1]);
  BAR_VM(0);
  COMPUTE(0);                 // j=255
  #undef BODY

  // ---- epilogue: out = tanh(acc + ext), C/D layout col=lane&15, row=lh*4+j ----
  #pragma unroll
  for (int mf = 0; mf < 2; ++mf)
    #pragma unroll
    for (int nf = 0; nf < 2; ++nf)
      #pragma unroll
      for (int j = 0; j < 4; ++j) {
        const int brow = wv * 32 + mf * 16 + lh * 4 + j;
        const int ocol = n0 + nf * 16 + lid;
        const size_t idx = ((size_t)(t * B_ + brow)) * H_ + ocol;
        out[idx] = tanhf(acc[mf][nf][j] + ext[idx]);
      }
}

// ================= fallback (no ws): round-3 structure, f32 A + cvt =================
__global__ __launch_bounds__(NTHR, 2)
void net_gemm_fb(const float* __restrict__ statesf,
                 const float* __restrict__ Wm,
                 const float* __restrict__ ext,
                 float* __restrict__ out)
{
  __shared__ __align__(16) uint8_t lds[2 * BUFB];

  const int tid  = threadIdx.x;
  const int bid  = blockIdx.x;
  const int t    = bid >> 7;
  const int n0   = (bid & 127) * BN;
  const int wv   = tid >> 6;
  const int lane = tid & 63;
  const int lid  = lane & 15;
  const int lh   = lane >> 4;

  const int arow = tid >> 3;
  const int acol = (tid & 7) * 8;
  const uint32_t a_st_off =
      (uint32_t)arow * 128 + (((uint32_t)(tid & 7) * 16) ^ ((uint32_t)(arow & 7) << 4));
  const float* af_base = statesf + (size_t)arow * H_ + acol;

  const int wrow = tid >> 4;
  const int wcol = (tid & 15) * 4;
  const float* w_base = Wm + ((size_t)t * L_ * H_ + (size_t)(n0 + wrow)) * H_ + wcol;
  const uint32_t w_st0 =
      (uint32_t)ABYTES + (uint32_t)wrow * 128 + (((uint32_t)(tid & 15) * 8) ^ ((uint32_t)(wrow & 7) << 4));
  const uint32_t w_st1 = w_st0 + 16 * 128;

  uint32_t a_rd[2][2], b_rd[2][2];
  #pragma unroll
  for (int mf = 0; mf < 2; ++mf)
    #pragma unroll
    for (int kk = 0; kk < 2; ++kk) {
      const int row = wv * 32 + mf * 16 + lid;
      a_rd[mf][kk] = (uint32_t)row * 128 +
                     (((uint32_t)(kk * 64 + lh * 16)) ^ ((uint32_t)(lid & 7) << 4));
    }
  #pragma unroll
  for (int nf = 0; nf < 2; ++nf)
    #pragma unroll
    for (int kk = 0; kk < 2; ++kk) {
      const int row = nf * 16 + lid;
      b_rd[nf][kk] = (uint32_t)ABYTES + (uint32_t)row * 128 +
                     (((uint32_t)(kk * 64 + lh * 16)) ^ ((uint32_t)(lid & 7) << 4));
    }

  f32x4 acc[2][2] = {};
  f4 af0[4][2], af1[4][2], wf0[2], wf1[2];

  auto LOADg = [&](int kidx, f4 (&af)[4][2], f4 (&wfx)[2]) {
    const int s  = kidx >> 6;
    const int h0 = (kidx & 63) << 6;
    const float* ap = af_base + (size_t)s * (B_ * H_) + h0;
    #pragma unroll
    for (int j = 0; j < 4; ++j) {
      af[j][0] = *reinterpret_cast<const f4*>(ap + (size_t)j * (32 * H_));
      af[j][1] = *reinterpret_cast<const f4*>(ap + (size_t)j * (32 * H_) + 4);
    }
    const float* wp = w_base + (size_t)s * ((size_t)H_ * H_) + h0;
    wfx[0] = __builtin_nontemporal_load(reinterpret_cast<const f4*>(wp));
    wfx[1] = __builtin_nontemporal_load(reinterpret_cast<const f4*>(wp + 16 * (size_t)H_));
  };

  auto WRITEg = [&](uint8_t* base, f4 (&af)[4][2], f4 (&wfx)[2]) {
    #pragma unroll
    for (int j = 0; j < 4; ++j) {
      u32x4 v;
      v.x = pack2(af[j][0].x, af[j][0].y);
      v.y = pack2(af[j][0].z, af[j][0].w);
      v.z = pack2(af[j][1].x, af[j][1].y);
      v.w = pack2(af[j][1].z, af[j][1].w);
      *reinterpret_cast<u32x4*>(base + j * 4096 + a_st_off) = v;
    }
    u32x2 w0, w1;
    w0.x = pack2(wfx[0].x, wfx[0].y); w0.y = pack2(wfx[0].z, wfx[0].w);
    w1.x = pack2(wfx[1].x, wfx[1].y); w1.y = pack2(wfx[1].z, wfx[1].w);
    *reinterpret_cast<u32x2*>(base + w_st0) = w0;
    *reinterpret_cast<u32x2*>(base + w_st1) = w1;
  };

  auto COMPUTE = [&](const uint8_t* base) {
    f16x8 av[2][2], bv[2][2];
    #pragma unroll
    for (int mf = 0; mf < 2; ++mf)
      #pragma unroll
      for (int kk = 0; kk < 2; ++kk)
        av[mf][kk] = *reinterpret_cast<const f16x8*>(base + a_rd[mf][kk]);
    #pragma unroll
    for (int nf = 0; nf < 2; ++nf)
      #pragma unroll
      for (int kk = 0; kk < 2; ++kk)
        bv[nf][kk] = *reinterpret_cast<const f16x8*>(base + b_rd[nf][kk]);
    #pragma unroll
    for (int kk = 0; kk < 2; ++kk)
      #pragma unroll
      for (int mf = 0; mf < 2; ++mf)
        #pragma unroll
        for (int nf = 0; nf < 2; ++nf)
          acc[mf][nf] = __builtin_amdgcn_mfma_f32_16x16x32_f16(
              av[mf][kk], bv[nf][kk], acc[mf][nf], 0, 0, 0);
  };

  uint8_t* buf0 = lds;
  uint8_t* buf1 = lds + BUFB;

  LOADg(0, af0, wf0);
  LOADg(1, af1, wf1);
  WRITEg(buf0, af0, wf0);
  BAR_VM(0);

  #pragma unroll 1
  for (int k = 0; k < KIT; k += 2) {
    if (k + 2 < KIT) LOADg(k + 2, af0, wf0);
    COMPUTE(buf0);
    WRITEg(buf1, af1, wf1);
    BAR_VM(0);
    if (k + 3 < KIT) LOADg(k + 3, af1, wf1);
    COMPUTE(buf1);
    if (k + 2 < KIT) {
      WRITEg(buf0, af0, wf0);
      BAR_VM(0);
    }
  }

  #pragma unroll
  for (int mf = 0; mf < 2; ++mf)
    #pragma unroll
    for (int nf = 0; nf < 2; ++nf)
      #pragma unroll
      for (int j = 0; j < 4; ++j) {
        const int brow = wv * 32 + mf * 16 + lh * 4 + j;
        const int ocol = n0 + nf * 16 + lid;
        const size_t idx = ((size_t)(t * B_ + brow)) * H_ + ocol;
        out[idx] = tanhf(acc[mf][nf][j] + ext[idx]);
      }
}

extern "C" void kernel_launch(void* const* d_in, const int* in_sizes, int n_in,
                              void* d_out, int out_size, void* d_ws, size_t ws_size,
                              hipStream_t stream) {
  const float* states = (const float*)d_in[0];
  const float* W      = (const float*)d_in[1];
  const float* ext    = (const float*)d_in[2];
  float* out          = (float*)d_out;

  const size_t nstates = (size_t)L_ * B_ * H_;       // 2,097,152 elements
  if (ws_size >= nstates * sizeof(uint16_t)) {
    const int n4 = (int)(nstates / 4);
    cvt_states_kernel<<<(n4 + 255) / 256, 256, 0, stream>>>(states, (uint32_t*)d_ws, n4);
    net_gemm_kernel<<<512, NTHR, 0, stream>>>((const uint16_t*)d_ws, W, ext, out);
  } else {
    net_gemm_fb<<<512, NTHR, 0, stream>>>(states, W, ext, out);
  }
}

// Round 6
// 257.086 us; speedup vs baseline: 1.6738x; 1.0316x over previous
//
#include <hip/hip_runtime.h>
#include <hip/hip_bf16.h>
#include <stdint.h>

#define L_ 4
#define B_ 128
#define H_ 4096
#define BK 64
#define BN 32
#define NTHR 256
#define NTOT (L_*B_*H_)       // 2,097,152 output elements
#define ABYTES (128*BK*2)     // 16384 B : A tile 128 x 64 fp16 (128 B rows)
#define WBYTES (BN*BK*2)      // 4096 B  : W tile 32 x 64 fp16 (128 B rows)
#define BUFB   (ABYTES+WBYTES)// 20480 B per buffer; x2 = 40960 -> 4 WGs/CU = 160 KB

typedef _Float16 f16x8 __attribute__((ext_vector_type(8)));
typedef float    f32x4 __attribute__((ext_vector_type(4)));
typedef float    f4    __attribute__((ext_vector_type(4)));
typedef uint32_t u32x4 __attribute__((ext_vector_type(4)));
typedef uint32_t u32x2 __attribute__((ext_vector_type(2)));

// RNE f32 -> fp16 pair packed into u32 (v_cvt_f16_f32 is round-nearest-even)
__device__ __forceinline__ uint32_t pack2(float a, float b) {
  const _Float16 ha = (_Float16)a;
  const _Float16 hb = (_Float16)b;
  const uint32_t ua = (uint32_t)__builtin_bit_cast(uint16_t, ha);
  const uint32_t ub = (uint32_t)__builtin_bit_cast(uint16_t, hb);
  return ua | (ub << 16);
}

__global__ void cvt_states_kernel(const float* __restrict__ x,
                                  uint32_t* __restrict__ y, int n4) {
  const int i = blockIdx.x * blockDim.x + threadIdx.x;
  if (i < n4) {
    f4 v = reinterpret_cast<const f4*>(x)[i];
    u32x2 o;
    o.x = pack2(v.x, v.y);
    o.y = pack2(v.z, v.w);
    reinterpret_cast<u32x2*>(y)[i] = o;
  }
}

// counted-wait barrier: own ds ops complete, global loads stay in flight.
__device__ __forceinline__ void bar_lgkm0() {
  __builtin_amdgcn_sched_barrier(0);
  asm volatile("s_waitcnt lgkmcnt(0)");
  __builtin_amdgcn_sched_barrier(0);
  __builtin_amdgcn_s_barrier();
  __builtin_amdgcn_sched_barrier(0);
}

// ===================== main GEMM (fp16 A from ws), optional split-K =====================
// SPLIT=1: grid 512,  full K, epilogue tanh(acc+ext) -> out
// SPLIT=2: grid 1024, half K (2 sources), epilogue partial f32 -> part[kh]
template<int SPLIT>
__global__ __launch_bounds__(NTHR, 2*SPLIT)
void net_gemm_kernel(const uint16_t* __restrict__ statesh,
                     const float* __restrict__ Wm,
                     const float* __restrict__ ext,
                     float* __restrict__ out,
                     float* __restrict__ part)
{
  constexpr int KITN = 256 / SPLIT;
  __shared__ __align__(16) uint8_t lds[2 * BUFB];   // 40 KB double-buffered

  const int tid  = threadIdx.x;
  const int bid  = blockIdx.x;
  const int n0   = (bid & 127) * BN;      // output-col tile
  const int t    = (bid >> 7) & 3;        // target layer
  const int kh   = bid >> 9;              // K-half (0 when SPLIT=1)
  const int sbase = kh * (L_ / SPLIT);

  const int wv   = tid >> 6;              // wave 0..3
  const int lane = tid & 63;
  const int lid  = lane & 15;
  const int lh   = lane >> 4;

  // ---- A staging map: thread -> (row group j*32+arow, 8 fp16 at acol) ----
  const int arow = tid >> 3;              // 0..31
  const int acol = (tid & 7) * 8;
  const uint32_t a_st_off =
      (uint32_t)arow * 128 + (((uint32_t)(tid & 7) * 16) ^ ((uint32_t)(arow & 7) << 4));
  const uint16_t* ah_base = statesh + (size_t)arow * H_ + acol;

  // ---- W staging map: rows (tid>>4) and +16, 4 f32 at col (tid&15)*4 ----
  const int wrow = tid >> 4;              // 0..15
  const int wcol = (tid & 15) * 4;
  const float* w_base = Wm + ((size_t)t * L_ * H_ + (size_t)(n0 + wrow)) * H_ + wcol;
  const uint32_t w_st0 =
      (uint32_t)ABYTES + (uint32_t)wrow * 128 + (((uint32_t)(tid & 15) * 8) ^ ((uint32_t)(wrow & 7) << 4));
  const uint32_t w_st1 = w_st0 + 16 * 128;

  // ---- LDS read offsets for MFMA fragments ----
  uint32_t a_rd[2][2], b_rd[2][2];
  #pragma unroll
  for (int mf = 0; mf < 2; ++mf)
    #pragma unroll
    for (int kk = 0; kk < 2; ++kk) {
      const int row = wv * 32 + mf * 16 + lid;
      a_rd[mf][kk] = (uint32_t)row * 128 +
                     (((uint32_t)(kk * 64 + lh * 16)) ^ ((uint32_t)(lid & 7) << 4));
    }
  #pragma unroll
  for (int nf = 0; nf < 2; ++nf)
    #pragma unroll
    for (int kk = 0; kk < 2; ++kk) {
      const int row = nf * 16 + lid;
      b_rd[nf][kk] = (uint32_t)ABYTES + (uint32_t)row * 128 +
                     (((uint32_t)(kk * 64 + lh * 16)) ^ ((uint32_t)(lid & 7) << 4));
    }

  f32x4 acc[2][2] = {};

  // two explicit register staging sets (static indexing only)
  u32x4 ah0[4], ah1[4];
  f4    wf0[2], wf1[2];

  auto LOADg = [&](int kidx, u32x4 (&ah)[4], f4 (&wf)[2]) {
    const int s  = sbase + (kidx >> 6);
    const int h0 = (kidx & 63) << 6;
    const uint16_t* ap = ah_base + (size_t)s * (B_ * H_) + h0;
    #pragma unroll
    for (int j = 0; j < 4; ++j)
      ah[j] = *reinterpret_cast<const u32x4*>(ap + (size_t)j * (32 * H_));
    const float* wp = w_base + (size_t)s * ((size_t)H_ * H_) + h0;
    wf[0] = __builtin_nontemporal_load(reinterpret_cast<const f4*>(wp));
    wf[1] = __builtin_nontemporal_load(reinterpret_cast<const f4*>(wp + 16 * (size_t)H_));
  };

  auto WRITEg = [&](uint8_t* base, u32x4 (&ah)[4], f4 (&wf)[2]) {
    #pragma unroll
    for (int j = 0; j < 4; ++j)
      *reinterpret_cast<u32x4*>(base + j * 4096 + a_st_off) = ah[j];
    u32x2 w0, w1;
    w0.x = pack2(wf[0].x, wf[0].y); w0.y = pack2(wf[0].z, wf[0].w);
    w1.x = pack2(wf[1].x, wf[1].y); w1.y = pack2(wf[1].z, wf[1].w);
    *reinterpret_cast<u32x2*>(base + w_st0) = w0;
    *reinterpret_cast<u32x2*>(base + w_st1) = w1;
  };

  auto COMPUTE = [&](const uint8_t* base) {
    f16x8 av[2][2], bv[2][2];
    #pragma unroll
    for (int mf = 0; mf < 2; ++mf)
      #pragma unroll
      for (int kk = 0; kk < 2; ++kk)
        av[mf][kk] = *reinterpret_cast<const f16x8*>(base + a_rd[mf][kk]);
    #pragma unroll
    for (int nf = 0; nf < 2; ++nf)
      #pragma unroll
      for (int kk = 0; kk < 2; ++kk)
        bv[nf][kk] = *reinterpret_cast<const f16x8*>(base + b_rd[nf][kk]);
    #pragma unroll
    for (int kk = 0; kk < 2; ++kk)
      #pragma unroll
      for (int mf = 0; mf < 2; ++mf)
        #pragma unroll
        for (int nf = 0; nf < 2; ++nf)
          acc[mf][nf] = __builtin_amdgcn_mfma_f32_16x16x32_f16(
              av[mf][kk], bv[nf][kk], acc[mf][nf], 0, 0, 0);
  };

  uint8_t* buf0 = lds;
  uint8_t* buf1 = lds + BUFB;

  // prologue: tiles 0 and 1 in flight; write tile 0
  LOADg(0, ah0, wf0);
  LOADg(1, ah1, wf1);
  WRITEg(buf0, ah0, wf0);   // reg-dep gives counted vmcnt (set1 stays in flight)
  bar_lgkm0();

  #pragma unroll 1
  for (int k = 0; k < KITN; k += 2) {
    // even: compute tile k (buf0); prefetch k+2; stage k+1
    if (k + 2 < KITN) LOADg(k + 2, ah0, wf0);
    COMPUTE(buf0);
    WRITEg(buf1, ah1, wf1);
    bar_lgkm0();

    // odd: compute tile k+1 (buf1); prefetch k+3; stage k+2
    if (k + 3 < KITN) LOADg(k + 3, ah1, wf1);
    COMPUTE(buf1);
    if (k + 2 < KITN) {
      WRITEg(buf0, ah0, wf0);
      bar_lgkm0();
    }
  }

  // ---- epilogue: C/D layout col=lane&15, row=lh*4+j ----
  #pragma unroll
  for (int mf = 0; mf < 2; ++mf)
    #pragma unroll
    for (int nf = 0; nf < 2; ++nf)
      #pragma unroll
      for (int j = 0; j < 4; ++j) {
        const int brow = wv * 32 + mf * 16 + lh * 4 + j;
        const int ocol = n0 + nf * 16 + lid;
        const size_t idx = ((size_t)(t * B_ + brow)) * H_ + ocol;
        if constexpr (SPLIT == 1) {
          out[idx] = tanhf(acc[mf][nf][j] + ext[idx]);
        } else {
          float* pb = part + (size_t)kh * NTOT;
          __builtin_nontemporal_store(acc[mf][nf][j], &pb[idx]);
        }
      }
}

// ===================== reduce: out = tanh(p0 + p1 + ext) =====================
__global__ __launch_bounds__(NTHR)
void reduce_kernel(const float* __restrict__ part,
                   const float* __restrict__ ext,
                   float* __restrict__ out)
{
  const int i = blockIdx.x * blockDim.x + threadIdx.x;   // f4 index, exact grid
  f4 p0 = __builtin_nontemporal_load(reinterpret_cast<const f4*>(part) + i);
  f4 p1 = __builtin_nontemporal_load(reinterpret_cast<const f4*>(part + NTOT) + i);
  f4 e  = reinterpret_cast<const f4*>(ext)[i];
  f4 r;
  r.x = tanhf(p0.x + p1.x + e.x);
  r.y = tanhf(p0.y + p1.y + e.y);
  r.z = tanhf(p0.z + p1.z + e.z);
  r.w = tanhf(p0.w + p1.w + e.w);
  reinterpret_cast<f4*>(out)[i] = r;
}

// ================= fallback (no ws): f32 A + cvt in-kernel =================
__global__ __launch_bounds__(NTHR, 2)
void net_gemm_fb(const float* __restrict__ statesf,
                 const float* __restrict__ Wm,
                 const float* __restrict__ ext,
                 float* __restrict__ out)
{
  __shared__ __align__(16) uint8_t lds[2 * BUFB];

  const int tid  = threadIdx.x;
  const int bid  = blockIdx.x;
  const int t    = bid >> 7;
  const int n0   = (bid & 127) * BN;
  const int wv   = tid >> 6;
  const int lane = tid & 63;
  const int lid  = lane & 15;
  const int lh   = lane >> 4;

  const int arow = tid >> 3;
  const int acol = (tid & 7) * 8;
  const uint32_t a_st_off =
      (uint32_t)arow * 128 + (((uint32_t)(tid & 7) * 16) ^ ((uint32_t)(arow & 7) << 4));
  const float* af_base = statesf + (size_t)arow * H_ + acol;

  const int wrow = tid >> 4;
  const int wcol = (tid & 15) * 4;
  const float* w_base = Wm + ((size_t)t * L_ * H_ + (size_t)(n0 + wrow)) * H_ + wcol;
  const uint32_t w_st0 =
      (uint32_t)ABYTES + (uint32_t)wrow * 128 + (((uint32_t)(tid & 15) * 8) ^ ((uint32_t)(wrow & 7) << 4));
  const uint32_t w_st1 = w_st0 + 16 * 128;

  uint32_t a_rd[2][2], b_rd[2][2];
  #pragma unroll
  for (int mf = 0; mf < 2; ++mf)
    #pragma unroll
    for (int kk = 0; kk < 2; ++kk) {
      const int row = wv * 32 + mf * 16 + lid;
      a_rd[mf][kk] = (uint32_t)row * 128 +
                     (((uint32_t)(kk * 64 + lh * 16)) ^ ((uint32_t)(lid & 7) << 4));
    }
  #pragma unroll
  for (int nf = 0; nf < 2; ++nf)
    #pragma unroll
    for (int kk = 0; kk < 2; ++kk) {
      const int row = nf * 16 + lid;
      b_rd[nf][kk] = (uint32_t)ABYTES + (uint32_t)row * 128 +
                     (((uint32_t)(kk * 64 + lh * 16)) ^ ((uint32_t)(lid & 7) << 4));
    }

  f32x4 acc[2][2] = {};
  f4 af0[4][2], af1[4][2], wf0[2], wf1[2];

  auto LOADg = [&](int kidx, f4 (&af)[4][2], f4 (&wfx)[2]) {
    const int s  = kidx >> 6;
    const int h0 = (kidx & 63) << 6;
    const float* ap = af_base + (size_t)s * (B_ * H_) + h0;
    #pragma unroll
    for (int j = 0; j < 4; ++j) {
      af[j][0] = *reinterpret_cast<const f4*>(ap + (size_t)j * (32 * H_));
      af[j][1] = *reinterpret_cast<const f4*>(ap + (size_t)j * (32 * H_) + 4);
    }
    const float* wp = w_base + (size_t)s * ((size_t)H_ * H_) + h0;
    wfx[0] = __builtin_nontemporal_load(reinterpret_cast<const f4*>(wp));
    wfx[1] = __builtin_nontemporal_load(reinterpret_cast<const f4*>(wp + 16 * (size_t)H_));
  };

  auto WRITEg = [&](uint8_t* base, f4 (&af)[4][2], f4 (&wfx)[2]) {
    #pragma unroll
    for (int j = 0; j < 4; ++j) {
      u32x4 v;
      v.x = pack2(af[j][0].x, af[j][0].y);
      v.y = pack2(af[j][0].z, af[j][0].w);
      v.z = pack2(af[j][1].x, af[j][1].y);
      v.w = pack2(af[j][1].z, af[j][1].w);
      *reinterpret_cast<u32x4*>(base + j * 4096 + a_st_off) = v;
    }
    u32x2 w0, w1;
    w0.x = pack2(wfx[0].x, wfx[0].y); w0.y = pack2(wfx[0].z, wfx[0].w);
    w1.x = pack2(wfx[1].x, wfx[1].y); w1.y = pack2(wfx[1].z, wfx[1].w);
    *reinterpret_cast<u32x2*>(base + w_st0) = w0;
    *reinterpret_cast<u32x2*>(base + w_st1) = w1;
  };

  auto COMPUTE = [&](const uint8_t* base) {
    f16x8 av[2][2], bv[2][2];
    #pragma unroll
    for (int mf = 0; mf < 2; ++mf)
      #pragma unroll
      for (int kk = 0; kk < 2; ++kk)
        av[mf][kk] = *reinterpret_cast<const f16x8*>(base + a_rd[mf][kk]);
    #pragma unroll
    for (int nf = 0; nf < 2; ++nf)
      #pragma unroll
      for (int kk = 0; kk < 2; ++kk)
        bv[nf][kk] = *reinterpret_cast<const f16x8*>(base + b_rd[nf][kk]);
    #pragma unroll
    for (int kk = 0; kk < 2; ++kk)
      #pragma unroll
      for (int mf = 0; mf < 2; ++mf)
        #pragma unroll
        for (int nf = 0; nf < 2; ++nf)
          acc[mf][nf] = __builtin_amdgcn_mfma_f32_16x16x32_f16(
              av[mf][kk], bv[nf][kk], acc[mf][nf], 0, 0, 0);
  };

  uint8_t* buf0 = lds;
  uint8_t* buf1 = lds + BUFB;

  LOADg(0, af0, wf0);
  LOADg(1, af1, wf1);
  WRITEg(buf0, af0, wf0);
  bar_lgkm0();

  #pragma unroll 1
  for (int k = 0; k < 256; k += 2) {
    if (k + 2 < 256) LOADg(k + 2, af0, wf0);
    COMPUTE(buf0);
    WRITEg(buf1, af1, wf1);
    bar_lgkm0();
    if (k + 3 < 256) LOADg(k + 3, af1, wf1);
    COMPUTE(buf1);
    if (k + 2 < 256) {
      WRITEg(buf0, af0, wf0);
      bar_lgkm0();
    }
  }

  #pragma unroll
  for (int mf = 0; mf < 2; ++mf)
    #pragma unroll
    for (int nf = 0; nf < 2; ++nf)
      #pragma unroll
      for (int j = 0; j < 4; ++j) {
        const int brow = wv * 32 + mf * 16 + lh * 4 + j;
        const int ocol = n0 + nf * 16 + lid;
        const size_t idx = ((size_t)(t * B_ + brow)) * H_ + ocol;
        out[idx] = tanhf(acc[mf][nf][j] + ext[idx]);
      }
}

extern "C" void kernel_launch(void* const* d_in, const int* in_sizes, int n_in,
                              void* d_out, int out_size, void* d_ws, size_t ws_size,
                              hipStream_t stream) {
  const float* states = (const float*)d_in[0];
  const float* W      = (const float*)d_in[1];
  const float* ext    = (const float*)d_in[2];
  float* out          = (float*)d_out;

  const size_t st_bytes   = (size_t)NTOT * 2;        // 4,194,304 : fp16 states
  const size_t part_bytes = (size_t)2 * NTOT * 4;    // 16,777,216: 2 K-half partials
  const int n4 = NTOT / 4;                           // 524,288

  if (ws_size >= st_bytes + part_bytes) {
    float* part = (float*)((uint8_t*)d_ws + st_bytes);
    cvt_states_kernel<<<n4 / 256, NTHR, 0, stream>>>(states, (uint32_t*)d_ws, n4);
    net_gemm_kernel<2><<<1024, NTHR, 0, stream>>>(
        (const uint16_t*)d_ws, W, ext, out, part);
    reduce_kernel<<<n4 / 256, NTHR, 0, stream>>>(part, ext, out);
  } else if (ws_size >= st_bytes) {
    cvt_states_kernel<<<n4 / 256, NTHR, 0, stream>>>(states, (uint32_t*)d_ws, n4);
    net_gemm_kernel<1><<<512, NTHR, 0, stream>>>(
        (const uint16_t*)d_ws, W, ext, out, nullptr);
  } else {
    net_gemm_fb<<<512, NTHR, 0, stream>>>(states, W, ext, out);
  }
}

// Round 7
// 242.763 us; speedup vs baseline: 1.7725x; 1.0590x over previous
//
#include <hip/hip_runtime.h>
#include <hip/hip_bf16.h>
#include <stdint.h>

#define L_ 4
#define B_ 128
#define H_ 4096
#define BK 64
#define BN 32
#define KIT 256               // L_*H_/BK
#define NTHR 256
#define NTOT (L_*B_*H_)       // 2,097,152 elements
#define WBYTES (BN*BK*2)      // 4096 B : W tile 32 x 64 fp16 (128 B rows)

typedef _Float16 f16x8 __attribute__((ext_vector_type(8)));
typedef float    f32x4 __attribute__((ext_vector_type(4)));
typedef float    f4    __attribute__((ext_vector_type(4)));
typedef uint32_t u32x4 __attribute__((ext_vector_type(4)));
typedef uint32_t u32x2 __attribute__((ext_vector_type(2)));

// RNE f32 -> fp16 pair packed into u32
__device__ __forceinline__ uint32_t pack2(float a, float b) {
  const _Float16 ha = (_Float16)a;
  const _Float16 hb = (_Float16)b;
  const uint32_t ua = (uint32_t)__builtin_bit_cast(uint16_t, ha);
  const uint32_t ub = (uint32_t)__builtin_bit_cast(uint16_t, hb);
  return ua | (ub << 16);
}

// ---- cvt + tile: ws fp16 layout [kt(256)][kk(2)][lh(4)][row(128)][e(8)]
//      element (s, row, k): kt = (s*H + k)/64... precisely s=kt>>6, kb=kt&63,
//      k = kb*64 + kk*32 + lh*8 + e. Dest 16B unit index d = ((kt*2+kk)*4+lh)*128+row.
__global__ __launch_bounds__(NTHR)
void cvt_tile_kernel(const float* __restrict__ x, u32x4* __restrict__ ws)
{
  const int d   = blockIdx.x * NTHR + threadIdx.x;   // 0..262143
  const int row = d & 127;
  const int lh  = (d >> 7) & 3;
  const int kk  = (d >> 9) & 1;
  const int kt  = d >> 10;            // 0..255
  const int s   = kt >> 6;
  const int kb  = kt & 63;
  const float* src = x + ((size_t)(s * B_ + row)) * H_ + kb * 64 + kk * 32 + lh * 8;
  f4 lo = *reinterpret_cast<const f4*>(src);
  f4 hi = *reinterpret_cast<const f4*>(src + 4);
  u32x4 v;
  v.x = pack2(lo.x, lo.y); v.y = pack2(lo.z, lo.w);
  v.z = pack2(hi.x, hi.y); v.w = pack2(hi.z, hi.w);
  ws[d] = v;
}

// counted-wait barrier: own ds ops complete, global loads stay in flight.
__device__ __forceinline__ void bar_lgkm0() {
  __builtin_amdgcn_sched_barrier(0);
  asm volatile("s_waitcnt lgkmcnt(0)");
  __builtin_amdgcn_sched_barrier(0);
  __builtin_amdgcn_s_barrier();
  __builtin_amdgcn_sched_barrier(0);
}

// =================== main GEMM: A direct-from-tiled-ws, LDS = W only ===================
__global__ __launch_bounds__(NTHR, 2)
void net_gemm_kernel(const uint8_t* __restrict__ atiled,   // fp16 tiled states
                     const float* __restrict__ Wm,
                     const float* __restrict__ ext,
                     float* __restrict__ out)
{
  __shared__ __align__(16) uint8_t lds[2 * WBYTES];   // 8 KB: W double-buffered

  const int tid  = threadIdx.x;
  const int bid  = blockIdx.x;
  const int t    = bid >> 7;              // 0..3
  const int n0   = (bid & 127) * BN;      // output-col tile

  const int wv   = tid >> 6;              // wave 0..3
  const int lane = tid & 63;
  const int lid  = lane & 15;
  const int lh   = lane >> 4;

  // ---- A fragment base: frag(mf,kk) of tile kt at
  //      atiled + kt*16384 + kk*8192 + lh*2048 + (wv*32+mf*16+lid)*16 ----
  const uint8_t* a_base = atiled + lh * 2048 + (wv * 32 + lid) * 16;

  // ---- W staging map: rows (tid>>4) and +16, 4 f32 at col (tid&15)*4 ----
  const int wrow = tid >> 4;              // 0..15
  const int wcol = (tid & 15) * 4;
  const float* w_base = Wm + ((size_t)t * L_ * H_ + (size_t)(n0 + wrow)) * H_ + wcol;
  const uint32_t w_st0 =
      (uint32_t)wrow * 128 + (((uint32_t)(tid & 15) * 8) ^ ((uint32_t)(wrow & 7) << 4));
  const uint32_t w_st1 = w_st0 + 16 * 128;

  // ---- LDS read offsets for W (B-operand) fragments ----
  uint32_t b_rd[2][2];
  #pragma unroll
  for (int nf = 0; nf < 2; ++nf)
    #pragma unroll
    for (int kk = 0; kk < 2; ++kk) {
      const int row = nf * 16 + lid;
      b_rd[nf][kk] = (uint32_t)row * 128 +
                     (((uint32_t)(kk * 64 + lh * 16)) ^ ((uint32_t)(lid & 7) << 4));
    }

  f32x4 acc[2][2] = {};

  // A register sets (period-3 rotation), W reg sets (period-2) — static indexing
  f16x8 aS0[2][2], aS1[2][2], aS2[2][2];
  f4    wf0[2], wf1[2];

  auto LOADA = [&](int kt, f16x8 (&a)[2][2]) {
    const uint8_t* p = a_base + (size_t)kt * 16384;
    a[0][0] = *reinterpret_cast<const f16x8*>(p);
    a[1][0] = *reinterpret_cast<const f16x8*>(p + 256);
    a[0][1] = *reinterpret_cast<const f16x8*>(p + 8192);
    a[1][1] = *reinterpret_cast<const f16x8*>(p + 8192 + 256);
  };

  auto LOADW = [&](int kidx, f4 (&w)[2]) {
    const int s  = kidx >> 6;
    const int h0 = (kidx & 63) << 6;
    const float* wp = w_base + (size_t)s * ((size_t)H_ * H_) + h0;
    w[0] = __builtin_nontemporal_load(reinterpret_cast<const f4*>(wp));
    w[1] = __builtin_nontemporal_load(reinterpret_cast<const f4*>(wp + 16 * (size_t)H_));
  };

  auto WRITEW = [&](uint8_t* base, f4 (&w)[2]) {
    u32x2 w0, w1;
    w0.x = pack2(w[0].x, w[0].y); w0.y = pack2(w[0].z, w[0].w);
    w1.x = pack2(w[1].x, w[1].y); w1.y = pack2(w[1].z, w[1].w);
    *reinterpret_cast<u32x2*>(base + w_st0) = w0;
    *reinterpret_cast<u32x2*>(base + w_st1) = w1;
  };

  auto COMPUTE = [&](const uint8_t* base, f16x8 (&av)[2][2]) {
    f16x8 bv[2][2];
    #pragma unroll
    for (int nf = 0; nf < 2; ++nf)
      #pragma unroll
      for (int kk = 0; kk < 2; ++kk)
        bv[nf][kk] = *reinterpret_cast<const f16x8*>(base + b_rd[nf][kk]);
    #pragma unroll
    for (int kk = 0; kk < 2; ++kk)
      #pragma unroll
      for (int mf = 0; mf < 2; ++mf)
        #pragma unroll
        for (int nf = 0; nf < 2; ++nf)
          acc[mf][nf] = __builtin_amdgcn_mfma_f32_16x16x32_f16(
              av[mf][kk], bv[nf][kk], acc[mf][nf], 0, 0, 0);
  };

  uint8_t* buf0 = lds;
  uint8_t* buf1 = lds + WBYTES;

  // prologue: W0,W1 + A0,A1 in flight; stage W0
  LOADW(0, wf0);
  LOADW(1, wf1);
  LOADA(0, aS0);
  LOADA(1, aS1);
  WRITEW(buf0, wf0);    // counted vmcnt: newer loads stay in flight
  bar_lgkm0();

  // iter j: LOADA(j+2)->a[(j+2)%3]; LOADW(j+2)->wf[j%2];
  //         COMPUTE(buf[j%2], a[j%3]); WRITEW(buf[(j+1)%2], wf[(j+1)%2]); bar
  #define BODY(j_, AL_, AU_, WL_, WW_, BU_, BW_) do { \
      LOADA((j_) + 2, AL_);                           \
      LOADW((j_) + 2, WL_);                           \
      COMPUTE(BU_, AU_);                              \
      WRITEW(BW_, WW_);                               \
      bar_lgkm0();                                    \
    } while (0)

  #pragma unroll 1
  for (int k = 0; k < 252; k += 6) {
    BODY(k + 0, aS2, aS0, wf0, wf1, buf0, buf1);
    BODY(k + 1, aS0, aS1, wf1, wf0, buf1, buf0);
    BODY(k + 2, aS1, aS2, wf0, wf1, buf0, buf1);
    BODY(k + 3, aS2, aS0, wf1, wf0, buf1, buf0);
    BODY(k + 4, aS0, aS1, wf0, wf1, buf0, buf1);
    BODY(k + 5, aS1, aS2, wf1, wf0, buf1, buf0);
  }
  // tail j = 252..255
  BODY(252, aS2, aS0, wf0, wf1, buf0, buf1);
  BODY(253, aS0, aS1, wf1, wf0, buf1, buf0);
  COMPUTE(buf0, aS2);          // j=254
  WRITEW(buf1, wf1);           // tile 255
  bar_lgkm0();
  COMPUTE(buf1, aS0);          // j=255
  #undef BODY

  // ---- epilogue: out = tanh(acc + ext), C/D layout col=lane&15, row=lh*4+j ----
  #pragma unroll
  for (int mf = 0; mf < 2; ++mf)
    #pragma unroll
    for (int nf = 0; nf < 2; ++nf)
      #pragma unroll
      for (int j = 0; j < 4; ++j) {
        const int brow = wv * 32 + mf * 16 + lh * 4 + j;
        const int ocol = n0 + nf * 16 + lid;
        const size_t idx = ((size_t)(t * B_ + brow)) * H_ + ocol;
        out[idx] = tanhf(acc[mf][nf][j] + ext[idx]);
      }
}

// ================= fallback (no ws): R3 structure, f32 A + cvt in-kernel =================
#define FB_ABYTES (128*BK*2)
#define FB_BUFB   (FB_ABYTES+WBYTES)
__global__ __launch_bounds__(NTHR, 2)
void net_gemm_fb(const float* __restrict__ statesf,
                 const float* __restrict__ Wm,
                 const float* __restrict__ ext,
                 float* __restrict__ out)
{
  __shared__ __align__(16) uint8_t lds[2 * FB_BUFB];

  const int tid  = threadIdx.x;
  const int bid  = blockIdx.x;
  const int t    = bid >> 7;
  const int n0   = (bid & 127) * BN;
  const int wv   = tid >> 6;
  const int lane = tid & 63;
  const int lid  = lane & 15;
  const int lh   = lane >> 4;

  const int arow = tid >> 3;
  const int acol = (tid & 7) * 8;
  const uint32_t a_st_off =
      (uint32_t)arow * 128 + (((uint32_t)(tid & 7) * 16) ^ ((uint32_t)(arow & 7) << 4));
  const float* af_base = statesf + (size_t)arow * H_ + acol;

  const int wrow = tid >> 4;
  const int wcol = (tid & 15) * 4;
  const float* w_base = Wm + ((size_t)t * L_ * H_ + (size_t)(n0 + wrow)) * H_ + wcol;
  const uint32_t w_st0 =
      (uint32_t)FB_ABYTES + (uint32_t)wrow * 128 + (((uint32_t)(tid & 15) * 8) ^ ((uint32_t)(wrow & 7) << 4));
  const uint32_t w_st1 = w_st0 + 16 * 128;

  uint32_t a_rd[2][2], b_rd[2][2];
  #pragma unroll
  for (int mf = 0; mf < 2; ++mf)
    #pragma unroll
    for (int kk = 0; kk < 2; ++kk) {
      const int row = wv * 32 + mf * 16 + lid;
      a_rd[mf][kk] = (uint32_t)row * 128 +
                     (((uint32_t)(kk * 64 + lh * 16)) ^ ((uint32_t)(lid & 7) << 4));
    }
  #pragma unroll
  for (int nf = 0; nf < 2; ++nf)
    #pragma unroll
    for (int kk = 0; kk < 2; ++kk) {
      const int row = nf * 16 + lid;
      b_rd[nf][kk] = (uint32_t)FB_ABYTES + (uint32_t)row * 128 +
                     (((uint32_t)(kk * 64 + lh * 16)) ^ ((uint32_t)(lid & 7) << 4));
    }

  f32x4 acc[2][2] = {};
  f4 af0[4][2], af1[4][2], wf0[2], wf1[2];

  auto LOADg = [&](int kidx, f4 (&af)[4][2], f4 (&wfx)[2]) {
    const int s  = kidx >> 6;
    const int h0 = (kidx & 63) << 6;
    const float* ap = af_base + (size_t)s * (B_ * H_) + h0;
    #pragma unroll
    for (int j = 0; j < 4; ++j) {
      af[j][0] = *reinterpret_cast<const f4*>(ap + (size_t)j * (32 * H_));
      af[j][1] = *reinterpret_cast<const f4*>(ap + (size_t)j * (32 * H_) + 4);
    }
    const float* wp = w_base + (size_t)s * ((size_t)H_ * H_) + h0;
    wfx[0] = __builtin_nontemporal_load(reinterpret_cast<const f4*>(wp));
    wfx[1] = __builtin_nontemporal_load(reinterpret_cast<const f4*>(wp + 16 * (size_t)H_));
  };

  auto WRITEg = [&](uint8_t* base, f4 (&af)[4][2], f4 (&wfx)[2]) {
    #pragma unroll
    for (int j = 0; j < 4; ++j) {
      u32x4 v;
      v.x = pack2(af[j][0].x, af[j][0].y);
      v.y = pack2(af[j][0].z, af[j][0].w);
      v.z = pack2(af[j][1].x, af[j][1].y);
      v.w = pack2(af[j][1].z, af[j][1].w);
      *reinterpret_cast<u32x4*>(base + j * 4096 + a_st_off) = v;
    }
    u32x2 w0, w1;
    w0.x = pack2(wfx[0].x, wfx[0].y); w0.y = pack2(wfx[0].z, wfx[0].w);
    w1.x = pack2(wfx[1].x, wfx[1].y); w1.y = pack2(wfx[1].z, wfx[1].w);
    *reinterpret_cast<u32x2*>(base + w_st0) = w0;
    *reinterpret_cast<u32x2*>(base + w_st1) = w1;
  };

  auto COMPUTE = [&](const uint8_t* base) {
    f16x8 av[2][2], bv[2][2];
    #pragma unroll
    for (int mf = 0; mf < 2; ++mf)
      #pragma unroll
      for (int kk = 0; kk < 2; ++kk)
        av[mf][kk] = *reinterpret_cast<const f16x8*>(base + a_rd[mf][kk]);
    #pragma unroll
    for (int nf = 0; nf < 2; ++nf)
      #pragma unroll
      for (int kk = 0; kk < 2; ++kk)
        bv[nf][kk] = *reinterpret_cast<const f16x8*>(base + b_rd[nf][kk]);
    #pragma unroll
    for (int kk = 0; kk < 2; ++kk)
      #pragma unroll
      for (int mf = 0; mf < 2; ++mf)
        #pragma unroll
        for (int nf = 0; nf < 2; ++nf)
          acc[mf][nf] = __builtin_amdgcn_mfma_f32_16x16x32_f16(
              av[mf][kk], bv[nf][kk], acc[mf][nf], 0, 0, 0);
  };

  uint8_t* buf0 = lds;
  uint8_t* buf1 = lds + FB_BUFB;

  LOADg(0, af0, wf0);
  LOADg(1, af1, wf1);
  WRITEg(buf0, af0, wf0);
  bar_lgkm0();

  #pragma unroll 1
  for (int k = 0; k < 256; k += 2) {
    if (k + 2 < 256) LOADg(k + 2, af0, wf0);
    COMPUTE(buf0);
    WRITEg(buf1, af1, wf1);
    bar_lgkm0();
    if (k + 3 < 256) LOADg(k + 3, af1, wf1);
    COMPUTE(buf1);
    if (k + 2 < 256) {
      WRITEg(buf0, af0, wf0);
      bar_lgkm0();
    }
  }

  #pragma unroll
  for (int mf = 0; mf < 2; ++mf)
    #pragma unroll
    for (int nf = 0; nf < 2; ++nf)
      #pragma unroll
      for (int j = 0; j < 4; ++j) {
        const int brow = wv * 32 + mf * 16 + lh * 4 + j;
        const int ocol = n0 + nf * 16 + lid;
        const size_t idx = ((size_t)(t * B_ + brow)) * H_ + ocol;
        out[idx] = tanhf(acc[mf][nf][j] + ext[idx]);
      }
}

extern "C" void kernel_launch(void* const* d_in, const int* in_sizes, int n_in,
                              void* d_out, int out_size, void* d_ws, size_t ws_size,
                              hipStream_t stream) {
  const float* states = (const float*)d_in[0];
  const float* W      = (const float*)d_in[1];
  const float* ext    = (const float*)d_in[2];
  float* out          = (float*)d_out;

  const size_t st_bytes = (size_t)NTOT * 2;          // 4,194,304 : fp16 tiled states
  if (ws_size >= st_bytes) {
    const int nunits = NTOT / 8;                     // 262,144 16-B units
    cvt_tile_kernel<<<nunits / NTHR, NTHR, 0, stream>>>(states, (u32x4*)d_ws);
    net_gemm_kernel<<<512, NTHR, 0, stream>>>(
        (const uint8_t*)d_ws, W, ext, out);
  } else {
    net_gemm_fb<<<512, NTHR, 0, stream>>>(states, W, ext, out);
  }
}

// Round 8
// 217.268 us; speedup vs baseline: 1.9805x; 1.1173x over previous
//
#include <hip/hip_runtime.h>
#include <hip/hip_bf16.h>
#include <stdint.h>

#define L_ 4
#define B_ 128
#define H_ 4096
#define BN 32
#define BKF 256               // K fetched per super-iter (1 KB/row chunks)
#define SUP 64                // super-iters = L_*H_/BKF
#define NTHR 256
#define NTOT (L_*B_*H_)       // 2,097,152 elements
#define WTB (BN*BKF*2)        // 16384 B : W tile 32 x 256 fp16 (512 B rows)

typedef _Float16 f16x8 __attribute__((ext_vector_type(8)));
typedef float    f32x4 __attribute__((ext_vector_type(4)));
typedef float    f4    __attribute__((ext_vector_type(4)));
typedef uint32_t u32x4 __attribute__((ext_vector_type(4)));
typedef uint32_t u32x2 __attribute__((ext_vector_type(2)));

// RNE f32 -> fp16 pair packed into u32
__device__ __forceinline__ uint32_t pack2(float a, float b) {
  const _Float16 ha = (_Float16)a;
  const _Float16 hb = (_Float16)b;
  const uint32_t ua = (uint32_t)__builtin_bit_cast(uint16_t, ha);
  const uint32_t ub = (uint32_t)__builtin_bit_cast(uint16_t, hb);
  return ua | (ub << 16);
}

// ---- cvt + tile A: ws fp16 layout [kt(256)][kk(2)][lh(4)][row(128)][e(8)] ----
__global__ __launch_bounds__(NTHR)
void cvt_tile_kernel(const float* __restrict__ x, u32x4* __restrict__ ws)
{
  const int d   = blockIdx.x * NTHR + threadIdx.x;   // 0..262143
  const int row = d & 127;
  const int lh  = (d >> 7) & 3;
  const int kk  = (d >> 9) & 1;
  const int kt  = d >> 10;            // 0..255
  const int s   = kt >> 6;
  const int kb  = kt & 63;
  const float* src = x + ((size_t)(s * B_ + row)) * H_ + kb * 64 + kk * 32 + lh * 8;
  f4 lo = *reinterpret_cast<const f4*>(src);
  f4 hi = *reinterpret_cast<const f4*>(src + 4);
  u32x4 v;
  v.x = pack2(lo.x, lo.y); v.y = pack2(lo.z, lo.w);
  v.z = pack2(hi.x, hi.y); v.w = pack2(hi.z, hi.w);
  ws[d] = v;
}

// counted-wait barrier: own ds ops complete, global loads stay in flight.
__device__ __forceinline__ void bar_lgkm0() {
  __builtin_amdgcn_sched_barrier(0);
  asm volatile("s_waitcnt lgkmcnt(0)");
  __builtin_amdgcn_sched_barrier(0);
  __builtin_amdgcn_s_barrier();
  __builtin_amdgcn_sched_barrier(0);
}

// ============ main GEMM: A direct-from-tiled-ws, W super-iter staged (1KB rows) ============
__global__ __launch_bounds__(NTHR, 2)
void net_gemm_kernel(const uint8_t* __restrict__ atiled,
                     const float* __restrict__ Wm,
                     const float* __restrict__ ext,
                     float* __restrict__ out)
{
  __shared__ __align__(16) uint8_t lds[2 * WTB];   // 32 KB: W double-buffered

  const int tid  = threadIdx.x;
  const int bid  = blockIdx.x;
  const int t    = bid >> 7;              // 0..3
  const int n0   = (bid & 127) * BN;      // output-col tile

  const int wv   = tid >> 6;              // wave 0..3
  const int lane = tid & 63;
  const int lid  = lane & 15;
  const int lh   = lane >> 4;

  // ---- A fragment base (tiled ws): frag(mf,kk) of k-tile kt at
  //      atiled + kt*16384 + kk*8192 + lh*2048 + (wv*32+mf*16+lid)*16 ----
  const uint8_t* a_base = atiled + lh * 2048 + (wv * 32 + lid) * 16;

  // ---- W source: wave wv owns rows n0+wv*8 .. +7; per instr one full 1KB row chunk ----
  const float* wp0 = Wm + (((size_t)t * L_) * H_ + (size_t)(n0 + wv * 8)) * H_ + lane * 4;

  // ---- LDS read offsets for W (B-operand) fragments; rows are 512 B ----
  uint32_t b_rd[2][2];
  #pragma unroll
  for (int nf = 0; nf < 2; ++nf)
    #pragma unroll
    for (int kk = 0; kk < 2; ++kk) {
      const uint32_t row = (uint32_t)(nf * 16 + lid);
      b_rd[nf][kk] = row * 512 +
                     (((uint32_t)(kk * 64 + lh * 16)) ^ (((uint32_t)lid & 7) << 4));
    }

  f32x4 acc[2][2] = {};

  f4    wRA[8], wRB[8];        // W reg staging, depth-2 (32 VGPR each)
  f16x8 aA[2][2], aB[2][2];    // A double buffer

  auto LOADW = [&](int j, f4 (&w)[8]) {
    const float* p = wp0 + (size_t)(j >> 4) * ((size_t)H_ * H_) + ((j & 15) << 8);
    #pragma unroll
    for (int i = 0; i < 8; ++i)
      w[i] = __builtin_nontemporal_load(reinterpret_cast<const f4*>(p + (size_t)i * H_));
  };

  auto WRITEW = [&](uint8_t* base, f4 (&w)[8]) {
    #pragma unroll
    for (int i = 0; i < 8; ++i) {
      u32x2 v;
      v.x = pack2(w[i].x, w[i].y);
      v.y = pack2(w[i].z, w[i].w);
      const uint32_t off = (uint32_t)wv * 4096 + (uint32_t)i * 512 +
                           (((uint32_t)lane * 8) ^ ((uint32_t)i << 4));
      *reinterpret_cast<u32x2*>(base + off) = v;
    }
  };

  auto LOADA = [&](int kt, f16x8 (&a)[2][2]) {
    const uint8_t* p = a_base + (size_t)kt * 16384;
    a[0][0] = *reinterpret_cast<const f16x8*>(p);
    a[1][0] = *reinterpret_cast<const f16x8*>(p + 256);
    a[0][1] = *reinterpret_cast<const f16x8*>(p + 8192);
    a[1][1] = *reinterpret_cast<const f16x8*>(p + 8192 + 256);
  };

  auto SUB = [&](const uint8_t* base, int skoff, f16x8 (&av)[2][2]) {
    f16x8 bv[2][2];
    #pragma unroll
    for (int nf = 0; nf < 2; ++nf)
      #pragma unroll
      for (int kk = 0; kk < 2; ++kk)
        bv[nf][kk] = *reinterpret_cast<const f16x8*>(base + b_rd[nf][kk] + skoff);
    #pragma unroll
    for (int kk = 0; kk < 2; ++kk)
      #pragma unroll
      for (int mf = 0; mf < 2; ++mf)
        #pragma unroll
        for (int nf = 0; nf < 2; ++nf)
          acc[mf][nf] = __builtin_amdgcn_mfma_f32_16x16x32_f16(
              av[mf][kk], bv[nf][kk], acc[mf][nf], 0, 0, 0);
  };

  uint8_t* buf0 = lds;
  uint8_t* buf1 = lds + WTB;

  // prologue: W(0),W(1) in regs + A(0); stage W(0) into LDS
  LOADW(0, wRA);
  LOADW(1, wRB);
  LOADA(0, aA);
  WRITEW(buf0, wRA);    // counted vmcnt: newer loads stay in flight
  bar_lgkm0();

  // super-iter j: LOADW(j+2); 4 sub-steps (A rotation, 1-ahead);
  //               WRITEW W(j+1) -> buf[(j+1)&1]; barrier
  #define BODY(j_, WLD_, WWT_, BUFC_, BUFW_) do {  \
      LOADW((j_) + 2, WLD_);                       \
      LOADA(4*(j_) + 1, aB); SUB(BUFC_, 0,   aA);  \
      LOADA(4*(j_) + 2, aA); SUB(BUFC_, 128, aB);  \
      LOADA(4*(j_) + 3, aB); SUB(BUFC_, 256, aA);  \
      LOADA(4*(j_) + 4, aA); SUB(BUFC_, 384, aB);  \
      WRITEW(BUFW_, WWT_);                         \
      bar_lgkm0();                                 \
    } while (0)

  #pragma unroll 1
  for (int j = 0; j < 62; j += 2) {
    BODY(j,     wRA, wRB, buf0, buf1);
    BODY(j + 1, wRB, wRA, buf1, buf0);
  }
  // j = 62 : no LOADW(64); still stage W(63)
  LOADA(249, aB); SUB(buf0, 0,   aA);
  LOADA(250, aA); SUB(buf0, 128, aB);
  LOADA(251, aB); SUB(buf0, 256, aA);
  LOADA(252, aA); SUB(buf0, 384, aB);
  WRITEW(buf1, wRB);
  bar_lgkm0();
  // j = 63 : compute only
  LOADA(253, aB); SUB(buf1, 0,   aA);
  LOADA(254, aA); SUB(buf1, 128, aB);
  LOADA(255, aB); SUB(buf1, 256, aA);
                  SUB(buf1, 384, aB);
  #undef BODY

  // ---- epilogue: out = tanh(acc + ext), C/D layout col=lane&15, row=lh*4+j ----
  #pragma unroll
  for (int mf = 0; mf < 2; ++mf)
    #pragma unroll
    for (int nf = 0; nf < 2; ++nf)
      #pragma unroll
      for (int j = 0; j < 4; ++j) {
        const int brow = wv * 32 + mf * 16 + lh * 4 + j;
        const int ocol = n0 + nf * 16 + lid;
        const size_t idx = ((size_t)(t * B_ + brow)) * H_ + ocol;
        out[idx] = tanhf(acc[mf][nf][j] + ext[idx]);
      }
}

// ================= fallback (no ws): R3 structure, f32 A + cvt in-kernel =================
#define FBK 64
#define FB_ABYTES (128*FBK*2)
#define FB_WBYTES (BN*FBK*2)
#define FB_BUFB   (FB_ABYTES+FB_WBYTES)
__global__ __launch_bounds__(NTHR, 2)
void net_gemm_fb(const float* __restrict__ statesf,
                 const float* __restrict__ Wm,
                 const float* __restrict__ ext,
                 float* __restrict__ out)
{
  __shared__ __align__(16) uint8_t lds[2 * FB_BUFB];

  const int tid  = threadIdx.x;
  const int bid  = blockIdx.x;
  const int t    = bid >> 7;
  const int n0   = (bid & 127) * BN;
  const int wv   = tid >> 6;
  const int lane = tid & 63;
  const int lid  = lane & 15;
  const int lh   = lane >> 4;

  const int arow = tid >> 3;
  const int acol = (tid & 7) * 8;
  const uint32_t a_st_off =
      (uint32_t)arow * 128 + (((uint32_t)(tid & 7) * 16) ^ ((uint32_t)(arow & 7) << 4));
  const float* af_base = statesf + (size_t)arow * H_ + acol;

  const int wrow = tid >> 4;
  const int wcol = (tid & 15) * 4;
  const float* w_base = Wm + ((size_t)t * L_ * H_ + (size_t)(n0 + wrow)) * H_ + wcol;
  const uint32_t w_st0 =
      (uint32_t)FB_ABYTES + (uint32_t)wrow * 128 + (((uint32_t)(tid & 15) * 8) ^ ((uint32_t)(wrow & 7) << 4));
  const uint32_t w_st1 = w_st0 + 16 * 128;

  uint32_t a_rd[2][2], b_rd[2][2];
  #pragma unroll
  for (int mf = 0; mf < 2; ++mf)
    #pragma unroll
    for (int kk = 0; kk < 2; ++kk) {
      const int row = wv * 32 + mf * 16 + lid;
      a_rd[mf][kk] = (uint32_t)row * 128 +
                     (((uint32_t)(kk * 64 + lh * 16)) ^ ((uint32_t)(lid & 7) << 4));
    }
  #pragma unroll
  for (int nf = 0; nf < 2; ++nf)
    #pragma unroll
    for (int kk = 0; kk < 2; ++kk) {
      const int row = nf * 16 + lid;
      b_rd[nf][kk] = (uint32_t)FB_ABYTES + (uint32_t)row * 128 +
                     (((uint32_t)(kk * 64 + lh * 16)) ^ ((uint32_t)(lid & 7) << 4));
    }

  f32x4 acc[2][2] = {};
  f4 af0[4][2], af1[4][2], wf0[2], wf1[2];

  auto LOADg = [&](int kidx, f4 (&af)[4][2], f4 (&wfx)[2]) {
    const int s  = kidx >> 6;
    const int h0 = (kidx & 63) << 6;
    const float* ap = af_base + (size_t)s * (B_ * H_) + h0;
    #pragma unroll
    for (int j = 0; j < 4; ++j) {
      af[j][0] = *reinterpret_cast<const f4*>(ap + (size_t)j * (32 * H_));
      af[j][1] = *reinterpret_cast<const f4*>(ap + (size_t)j * (32 * H_) + 4);
    }
    const float* wp = w_base + (size_t)s * ((size_t)H_ * H_) + h0;
    wfx[0] = __builtin_nontemporal_load(reinterpret_cast<const f4*>(wp));
    wfx[1] = __builtin_nontemporal_load(reinterpret_cast<const f4*>(wp + 16 * (size_t)H_));
  };

  auto WRITEg = [&](uint8_t* base, f4 (&af)[4][2], f4 (&wfx)[2]) {
    #pragma unroll
    for (int j = 0; j < 4; ++j) {
      u32x4 v;
      v.x = pack2(af[j][0].x, af[j][0].y);
      v.y = pack2(af[j][0].z, af[j][0].w);
      v.z = pack2(af[j][1].x, af[j][1].y);
      v.w = pack2(af[j][1].z, af[j][1].w);
      *reinterpret_cast<u32x4*>(base + j * 4096 + a_st_off) = v;
    }
    u32x2 w0, w1;
    w0.x = pack2(wfx[0].x, wfx[0].y); w0.y = pack2(wfx[0].z, wfx[0].w);
    w1.x = pack2(wfx[1].x, wfx[1].y); w1.y = pack2(wfx[1].z, wfx[1].w);
    *reinterpret_cast<u32x2*>(base + w_st0) = w0;
    *reinterpret_cast<u32x2*>(base + w_st1) = w1;
  };

  auto COMPUTE = [&](const uint8_t* base) {
    f16x8 av[2][2], bv[2][2];
    #pragma unroll
    for (int mf = 0; mf < 2; ++mf)
      #pragma unroll
      for (int kk = 0; kk < 2; ++kk)
        av[mf][kk] = *reinterpret_cast<const f16x8*>(base + a_rd[mf][kk]);
    #pragma unroll
    for (int nf = 0; nf < 2; ++nf)
      #pragma unroll
      for (int kk = 0; kk < 2; ++kk)
        bv[nf][kk] = *reinterpret_cast<const f16x8*>(base + b_rd[nf][kk]);
    #pragma unroll
    for (int kk = 0; kk < 2; ++kk)
      #pragma unroll
      for (int mf = 0; mf < 2; ++mf)
        #pragma unroll
        for (int nf = 0; nf < 2; ++nf)
          acc[mf][nf] = __builtin_amdgcn_mfma_f32_16x16x32_f16(
              av[mf][kk], bv[nf][kk], acc[mf][nf], 0, 0, 0);
  };

  uint8_t* buf0 = lds;
  uint8_t* buf1 = lds + FB_BUFB;

  LOADg(0, af0, wf0);
  LOADg(1, af1, wf1);
  WRITEg(buf0, af0, wf0);
  bar_lgkm0();

  #pragma unroll 1
  for (int k = 0; k < 256; k += 2) {
    if (k + 2 < 256) LOADg(k + 2, af0, wf0);
    COMPUTE(buf0);
    WRITEg(buf1, af1, wf1);
    bar_lgkm0();
    if (k + 3 < 256) LOADg(k + 3, af1, wf1);
    COMPUTE(buf1);
    if (k + 2 < 256) {
      WRITEg(buf0, af0, wf0);
      bar_lgkm0();
    }
  }

  #pragma unroll
  for (int mf = 0; mf < 2; ++mf)
    #pragma unroll
    for (int nf = 0; nf < 2; ++nf)
      #pragma unroll
      for (int j = 0; j < 4; ++j) {
        const int brow = wv * 32 + mf * 16 + lh * 4 + j;
        const int ocol = n0 + nf * 16 + lid;
        const size_t idx = ((size_t)(t * B_ + brow)) * H_ + ocol;
        out[idx] = tanhf(acc[mf][nf][j] + ext[idx]);
      }
}

extern "C" void kernel_launch(void* const* d_in, const int* in_sizes, int n_in,
                              void* d_out, int out_size, void* d_ws, size_t ws_size,
                              hipStream_t stream) {
  const float* states = (const float*)d_in[0];
  const float* W      = (const float*)d_in[1];
  const float* ext    = (const float*)d_in[2];
  float* out          = (float*)d_out;

  const size_t st_bytes = (size_t)NTOT * 2;          // 4,194,304 : fp16 tiled states
  if (ws_size >= st_bytes) {
    const int nunits = NTOT / 8;                     // 262,144 16-B units
    cvt_tile_kernel<<<nunits / NTHR, NTHR, 0, stream>>>(states, (u32x4*)d_ws);
    net_gemm_kernel<<<512, NTHR, 0, stream>>>(
        (const uint8_t*)d_ws, W, ext, out);
  } else {
    net_gemm_fb<<<512, NTHR, 0, stream>>>(states, W, ext, out);
  }
}